// Round 1
// baseline (756.347 us; speedup 1.0000x reference)
//
#include <hip/hip_runtime.h>

// Problem constants (from reference): B=8, C=512, Cq=64, W=2048.
#define B_  8
#define C_  512
#define CQ_ 64
#define W_  2048

// Workspace layout (floats). Total = 44,072,960 floats = 176.3 MB.
static constexpr size_t OFF_Q = 0;                                  // [B][CQ][W]
static constexpr size_t OFF_K = OFF_Q + (size_t)B_ * CQ_ * W_;      // [B][CQ][W]
static constexpr size_t OFF_V = OFF_K + (size_t)B_ * CQ_ * W_;      // [B][C][W]
static constexpr size_t OFF_E = OFF_V + (size_t)B_ * C_ * W_;       // [B][W][W]
static constexpr size_t OFF_M = OFF_E + (size_t)B_ * W_ * W_;       // [B][W]
static constexpr size_t OFF_S = OFF_M + (size_t)B_ * W_;            // [B][W]

// ---------------------------------------------------------------------------
// Kernel 1: fused QKV projection (1x1 conv == channel-mixing GEMM).
// grid: (W/128, 10, B). blockIdx.y: 0->q, 1->k, 2..9 -> v row-tiles.
// Block tile: 64 out-rows x 128 out-cols, K staged in 64-chunks via LDS.
// ---------------------------------------------------------------------------
__global__ __launch_bounds__(256) void k_proj(
    const float* __restrict__ x,
    const float* __restrict__ Wq, const float* __restrict__ bq,
    const float* __restrict__ Wk, const float* __restrict__ bk,
    const float* __restrict__ Wv, const float* __restrict__ bv,
    float* __restrict__ qo, float* __restrict__ ko, float* __restrict__ vo)
{
    const int b  = blockIdx.z;
    const int rt = blockIdx.y;
    const int w0 = blockIdx.x * 128;

    const float* Wm; const float* bias; float* outp; int r0;
    if (rt == 0)      { Wm = Wq; bias = bq; outp = qo + (size_t)b * CQ_ * W_; r0 = 0; }
    else if (rt == 1) { Wm = Wk; bias = bk; outp = ko + (size_t)b * CQ_ * W_; r0 = 0; }
    else              { Wm = Wv; bias = bv; outp = vo + (size_t)b * C_ * W_;  r0 = (rt - 2) * 64; }

    __shared__ __align__(16) float xs[64][132];  // [c][w] direct copy
    __shared__ __align__(16) float wt[64][68];   // [c][r] transposed

    const int t  = threadIdx.x;
    const int tx = t & 15, ty = t >> 4;

    float acc[4][8];
    #pragma unroll
    for (int i = 0; i < 4; ++i)
        #pragma unroll
        for (int j = 0; j < 8; ++j) acc[i][j] = 0.f;

    for (int ct = 0; ct < 8; ++ct) {
        const float* xsrc = x + ((size_t)b * C_ + ct * 64) * W_ + w0;
        #pragma unroll
        for (int m = 0; m < 8; ++m) {
            int fi = m * 256 + t;
            int cc = fi >> 5;          // 32 float4 per 128-wide row
            int wq = fi & 31;
            *reinterpret_cast<float4*>(&xs[cc][wq * 4]) =
                *reinterpret_cast<const float4*>(xsrc + (size_t)cc * W_ + wq * 4);
        }
        const float* wsrc = Wm + (size_t)r0 * C_ + ct * 64;
        #pragma unroll
        for (int m = 0; m < 4; ++m) {
            int fi = m * 256 + t;      // 64 rows x 16 float4
            int r  = fi >> 4;
            int cq = fi & 15;
            float4 vv = *reinterpret_cast<const float4*>(wsrc + (size_t)r * C_ + cq * 4);
            wt[cq * 4 + 0][r] = vv.x;
            wt[cq * 4 + 1][r] = vv.y;
            wt[cq * 4 + 2][r] = vv.z;
            wt[cq * 4 + 3][r] = vv.w;
        }
        __syncthreads();
        #pragma unroll 8
        for (int kk = 0; kk < 64; ++kk) {
            float4 w4 = *reinterpret_cast<const float4*>(&wt[kk][ty * 4]);
            float4 xa = *reinterpret_cast<const float4*>(&xs[kk][tx * 4]);
            float4 xb = *reinterpret_cast<const float4*>(&xs[kk][64 + tx * 4]);
            float wr[4] = {w4.x, w4.y, w4.z, w4.w};
            float xv[8] = {xa.x, xa.y, xa.z, xa.w, xb.x, xb.y, xb.z, xb.w};
            #pragma unroll
            for (int i = 0; i < 4; ++i)
                #pragma unroll
                for (int j = 0; j < 8; ++j)
                    acc[i][j] = fmaf(wr[i], xv[j], acc[i][j]);
        }
        __syncthreads();
    }

    #pragma unroll
    for (int i = 0; i < 4; ++i) {
        int r = r0 + ty * 4 + i;
        float bb = bias[r];
        float* orow = outp + (size_t)r * W_ + w0;
        float4 o0 = make_float4(acc[i][0] + bb, acc[i][1] + bb, acc[i][2] + bb, acc[i][3] + bb);
        float4 o1 = make_float4(acc[i][4] + bb, acc[i][5] + bb, acc[i][6] + bb, acc[i][7] + bb);
        *reinterpret_cast<float4*>(orow + tx * 4) = o0;
        *reinterpret_cast<float4*>(orow + 64 + tx * 4) = o1;
    }
}

// ---------------------------------------------------------------------------
// Kernel 2: energy E[b,i,j] = sum_q q[b,q,i]*k[b,q,j]. 128x128 tile, K=64.
// grid: (W/128 j-tiles, W/128 i-tiles, B)
// ---------------------------------------------------------------------------
__global__ __launch_bounds__(256) void k_energy(
    const float* __restrict__ q, const float* __restrict__ k, float* __restrict__ E)
{
    const int b  = blockIdx.z;
    const int i0 = blockIdx.y * 128;
    const int j0 = blockIdx.x * 128;

    __shared__ __align__(16) float qs[64][132];
    __shared__ __align__(16) float ks[64][132];

    const int t  = threadIdx.x;
    const int tx = t & 15, ty = t >> 4;

    const float* qsrc = q + (size_t)b * CQ_ * W_ + i0;
    const float* ksrc = k + (size_t)b * CQ_ * W_ + j0;
    #pragma unroll
    for (int m = 0; m < 8; ++m) {
        int fi = m * 256 + t;
        int qq = fi >> 5;
        int iq = fi & 31;
        *reinterpret_cast<float4*>(&qs[qq][iq * 4]) =
            *reinterpret_cast<const float4*>(qsrc + (size_t)qq * W_ + iq * 4);
        *reinterpret_cast<float4*>(&ks[qq][iq * 4]) =
            *reinterpret_cast<const float4*>(ksrc + (size_t)qq * W_ + iq * 4);
    }
    __syncthreads();

    float acc[8][8];
    #pragma unroll
    for (int i = 0; i < 8; ++i)
        #pragma unroll
        for (int j = 0; j < 8; ++j) acc[i][j] = 0.f;

    #pragma unroll 8
    for (int kk = 0; kk < 64; ++kk) {
        float4 qa = *reinterpret_cast<const float4*>(&qs[kk][ty * 4]);
        float4 qb = *reinterpret_cast<const float4*>(&qs[kk][64 + ty * 4]);
        float4 ka = *reinterpret_cast<const float4*>(&ks[kk][tx * 4]);
        float4 kb = *reinterpret_cast<const float4*>(&ks[kk][64 + tx * 4]);
        float qv[8] = {qa.x, qa.y, qa.z, qa.w, qb.x, qb.y, qb.z, qb.w};
        float kv[8] = {ka.x, ka.y, ka.z, ka.w, kb.x, kb.y, kb.z, kb.w};
        #pragma unroll
        for (int i = 0; i < 8; ++i)
            #pragma unroll
            for (int j = 0; j < 8; ++j)
                acc[i][j] = fmaf(qv[i], kv[j], acc[i][j]);
    }

    float* erow0 = E + ((size_t)b * W_ + i0) * W_ + j0;
    #pragma unroll
    for (int ih = 0; ih < 8; ++ih) {
        int ii = ((ih & 4) << 4) + ty * 4 + (ih & 3);
        float* er = erow0 + (size_t)ii * W_;
        float4 o0 = make_float4(acc[ih][0], acc[ih][1], acc[ih][2], acc[ih][3]);
        float4 o1 = make_float4(acc[ih][4], acc[ih][5], acc[ih][6], acc[ih][7]);
        *reinterpret_cast<float4*>(er + tx * 4) = o0;
        *reinterpret_cast<float4*>(er + 64 + tx * 4) = o1;
    }
}

// ---------------------------------------------------------------------------
// Kernel 3: per-row softmax stats: m = max_j E, sinv = 1/sum_j exp(E-m).
// grid: (W, B); one 256-thread block per row.
// ---------------------------------------------------------------------------
__global__ __launch_bounds__(256) void k_stats(const float* __restrict__ E,
                                               float* __restrict__ mrow,
                                               float* __restrict__ srow)
{
    const int i = blockIdx.x;
    const int b = blockIdx.y;
    const float* row = E + ((size_t)b * W_ + i) * W_;
    const int t = threadIdx.x;

    float v8[8];
    float lm = -3.0e38f;
    #pragma unroll
    for (int m = 0; m < 8; ++m) {
        v8[m] = row[m * 256 + t];
        lm = fmaxf(lm, v8[m]);
    }
    #pragma unroll
    for (int off = 32; off >= 1; off >>= 1)
        lm = fmaxf(lm, __shfl_xor(lm, off));

    __shared__ float red[8];
    const int wv = t >> 6;
    if ((t & 63) == 0) red[wv] = lm;
    __syncthreads();
    float bm = fmaxf(fmaxf(red[0], red[1]), fmaxf(red[2], red[3]));

    float ls = 0.f;
    #pragma unroll
    for (int m = 0; m < 8; ++m) ls += __expf(v8[m] - bm);
    #pragma unroll
    for (int off = 32; off >= 1; off >>= 1)
        ls += __shfl_xor(ls, off);
    if ((t & 63) == 0) red[4 + wv] = ls;
    __syncthreads();
    if (t == 0) {
        float bs = red[4] + red[5] + red[6] + red[7];
        mrow[(size_t)b * W_ + i] = bm;
        srow[(size_t)b * W_ + i] = 1.0f / bs;
    }
}

// ---------------------------------------------------------------------------
// Kernel 4: out[b,c,i] = gamma * sum_j v[b,c,j]*softmax(E)[b,i,j] + x[b,c,i]
// Probabilities computed on the fly from (E, m, sinv). 128c x 128i tile,
// j staged in 64-chunks; LDS stored j-major so inner reads are ds_read_b128.
// grid: (W/128 i-tiles, C/128 c-tiles, B)
// ---------------------------------------------------------------------------
__global__ __launch_bounds__(256) void k_pv(
    const float* __restrict__ v, const float* __restrict__ E,
    const float* __restrict__ mrow, const float* __restrict__ srow,
    const float* __restrict__ x, const float* __restrict__ gamma,
    float* __restrict__ out)
{
    const int b  = blockIdx.z;
    const int c0 = blockIdx.y * 128;
    const int i0 = blockIdx.x * 128;

    __shared__ __align__(16) float vs[64][132];  // [j][c]
    __shared__ __align__(16) float es[64][132];  // [j][i]

    const int t  = threadIdx.x;
    const int tx = t & 15, ty = t >> 4;

    float acc[8][8];
    #pragma unroll
    for (int i = 0; i < 8; ++i)
        #pragma unroll
        for (int j = 0; j < 8; ++j) acc[i][j] = 0.f;

    const float* vbase = v + ((size_t)b * C_ + c0) * W_;
    const float* ebase = E + ((size_t)b * W_ + i0) * W_;
    const float* mb = mrow + (size_t)b * W_ + i0;
    const float* sb = srow + (size_t)b * W_ + i0;

    for (int jt = 0; jt < 32; ++jt) {
        const int j0 = jt * 64;
        #pragma unroll
        for (int m = 0; m < 8; ++m) {
            int fi = m * 256 + t;
            int cc = fi >> 4;          // 16 float4 per 64-wide row
            int jq = fi & 15;
            float4 vv = *reinterpret_cast<const float4*>(vbase + (size_t)cc * W_ + j0 + jq * 4);
            vs[jq * 4 + 0][cc] = vv.x;
            vs[jq * 4 + 1][cc] = vv.y;
            vs[jq * 4 + 2][cc] = vv.z;
            vs[jq * 4 + 3][cc] = vv.w;
        }
        #pragma unroll
        for (int m = 0; m < 8; ++m) {
            int fi = m * 256 + t;
            int ii = fi >> 4;
            int jq = fi & 15;
            float4 ev = *reinterpret_cast<const float4*>(ebase + (size_t)ii * W_ + j0 + jq * 4);
            float mi = mb[ii];
            float si = sb[ii];
            es[jq * 4 + 0][ii] = __expf(ev.x - mi) * si;
            es[jq * 4 + 1][ii] = __expf(ev.y - mi) * si;
            es[jq * 4 + 2][ii] = __expf(ev.z - mi) * si;
            es[jq * 4 + 3][ii] = __expf(ev.w - mi) * si;
        }
        __syncthreads();
        #pragma unroll 8
        for (int jj = 0; jj < 64; ++jj) {
            float4 va = *reinterpret_cast<const float4*>(&vs[jj][ty * 4]);
            float4 vb = *reinterpret_cast<const float4*>(&vs[jj][64 + ty * 4]);
            float4 ea = *reinterpret_cast<const float4*>(&es[jj][tx * 4]);
            float4 eb = *reinterpret_cast<const float4*>(&es[jj][64 + tx * 4]);
            float cv[8] = {va.x, va.y, va.z, va.w, vb.x, vb.y, vb.z, vb.w};
            float pv[8] = {ea.x, ea.y, ea.z, ea.w, eb.x, eb.y, eb.z, eb.w};
            #pragma unroll
            for (int ci = 0; ci < 8; ++ci)
                #pragma unroll
                for (int ij = 0; ij < 8; ++ij)
                    acc[ci][ij] = fmaf(cv[ci], pv[ij], acc[ci][ij]);
        }
        __syncthreads();
    }

    const float g = gamma[0];
    #pragma unroll
    for (int ch = 0; ch < 8; ++ch) {
        int cc = ((ch & 4) << 4) + ty * 4 + (ch & 3);
        const float* xr   = x   + ((size_t)b * C_ + c0 + cc) * W_ + i0;
        float*       orow = out + ((size_t)b * C_ + c0 + cc) * W_ + i0;
        float4 xa = *reinterpret_cast<const float4*>(xr + tx * 4);
        float4 xb = *reinterpret_cast<const float4*>(xr + 64 + tx * 4);
        float4 o0 = make_float4(g * acc[ch][0] + xa.x, g * acc[ch][1] + xa.y,
                                g * acc[ch][2] + xa.z, g * acc[ch][3] + xa.w);
        float4 o1 = make_float4(g * acc[ch][4] + xb.x, g * acc[ch][5] + xb.y,
                                g * acc[ch][6] + xb.z, g * acc[ch][7] + xb.w);
        *reinterpret_cast<float4*>(orow + tx * 4) = o0;
        *reinterpret_cast<float4*>(orow + 64 + tx * 4) = o1;
    }
}

// ---------------------------------------------------------------------------
extern "C" void kernel_launch(void* const* d_in, const int* in_sizes, int n_in,
                              void* d_out, int out_size, void* d_ws, size_t ws_size,
                              hipStream_t stream)
{
    const float* x     = (const float*)d_in[0];
    const float* Wq    = (const float*)d_in[1];
    const float* bq    = (const float*)d_in[2];
    const float* Wk    = (const float*)d_in[3];
    const float* bk    = (const float*)d_in[4];
    const float* Wv    = (const float*)d_in[5];
    const float* bv    = (const float*)d_in[6];
    const float* gamma = (const float*)d_in[7];
    float* out = (float*)d_out;
    float* ws  = (float*)d_ws;

    // Requires ws_size >= 176.3 MB (q,k,v,E,m,s). See offsets above.
    float* q    = ws + OFF_Q;
    float* k    = ws + OFF_K;
    float* v    = ws + OFF_V;
    float* E    = ws + OFF_E;
    float* mrow = ws + OFF_M;
    float* srow = ws + OFF_S;

    hipLaunchKernelGGL(k_proj,   dim3(W_ / 128, 10, B_), dim3(256), 0, stream,
                       x, Wq, bq, Wk, bk, Wv, bv, q, k, v);
    hipLaunchKernelGGL(k_energy, dim3(W_ / 128, W_ / 128, B_), dim3(256), 0, stream,
                       q, k, E);
    hipLaunchKernelGGL(k_stats,  dim3(W_, B_, 1), dim3(256), 0, stream,
                       E, mrow, srow);
    hipLaunchKernelGGL(k_pv,     dim3(W_ / 128, C_ / 128, B_), dim3(256), 0, stream,
                       v, E, mrow, srow, x, gamma, out);
}

// Round 4
// 369.919 us; speedup vs baseline: 2.0446x; 2.0446x over previous
//
#include <hip/hip_runtime.h>

// Problem constants: B=8, C=512, Cq=64, W=2048.
#define B_  8
#define C_  512
#define CQ_ 64
#define W_  2048

typedef __attribute__((ext_vector_type(8))) short  short8;   // 8 bf16 (MFMA A/B frag)
typedef __attribute__((ext_vector_type(4))) float  f32x4;    // MFMA C/D frag
typedef unsigned short ushort;

// Workspace layout (float slots). Total = 39,878,656 floats = 159.5 MB.
static constexpr size_t OFF_Q  = 0;                                  // q fp32 [B][64][W]
static constexpr size_t OFF_K  = OFF_Q  + (size_t)B_ * CQ_ * W_;     // k fp32 [B][64][W]
static constexpr size_t OFF_VB = OFF_K  + (size_t)B_ * CQ_ * W_;     // V bf16 [B][C][W]
static constexpr size_t OFF_E  = OFF_VB + (size_t)B_ * C_ * W_ / 2;  // E fp32 [B][W][W]
static constexpr size_t OFF_M  = OFF_E  + (size_t)B_ * W_ * W_;      // m [B][W]
static constexpr size_t OFF_S  = OFF_M  + (size_t)B_ * W_;           // sinv [B][W]

static __device__ __forceinline__ ushort f2bf(float f) {
    unsigned int u = __builtin_bit_cast(unsigned int, f);
    u += 0x7fffu + ((u >> 16) & 1u);          // round-to-nearest-even
    return (ushort)(u >> 16);
}

// ---------------------------------------------------------------------------
// Kernel 1: fused QKV projection. q,k written fp32 [64][W]; V written bf16.
// grid: (W/128, 10, B). blockIdx.y: 0->q, 1->k, 2..9 -> v row-tiles.
// ---------------------------------------------------------------------------
__global__ __launch_bounds__(256) void k_proj(
    const float* __restrict__ x,
    const float* __restrict__ Wq, const float* __restrict__ bq,
    const float* __restrict__ Wk, const float* __restrict__ bk,
    const float* __restrict__ Wv, const float* __restrict__ bv,
    float* __restrict__ qo, float* __restrict__ ko, ushort* __restrict__ vb)
{
    const int b  = blockIdx.z;
    const int rt = blockIdx.y;
    const int w0 = blockIdx.x * 128;

    const float* Wm; const float* bias; int r0;
    if (rt == 0)      { Wm = Wq; bias = bq; r0 = 0; }
    else if (rt == 1) { Wm = Wk; bias = bk; r0 = 0; }
    else              { Wm = Wv; bias = bv; r0 = (rt - 2) * 64; }

    __shared__ __align__(16) float xs[64][132];
    __shared__ __align__(16) float wt[64][68];

    const int t  = threadIdx.x;
    const int tx = t & 15, ty = t >> 4;

    float acc[4][8];
    #pragma unroll
    for (int i = 0; i < 4; ++i)
        #pragma unroll
        for (int j = 0; j < 8; ++j) acc[i][j] = 0.f;

    for (int ct = 0; ct < 8; ++ct) {
        const float* xsrc = x + ((size_t)b * C_ + ct * 64) * W_ + w0;
        #pragma unroll
        for (int m = 0; m < 8; ++m) {
            int fi = m * 256 + t;
            int cc = fi >> 5;
            int wq = fi & 31;
            *reinterpret_cast<float4*>(&xs[cc][wq * 4]) =
                *reinterpret_cast<const float4*>(xsrc + (size_t)cc * W_ + wq * 4);
        }
        const float* wsrc = Wm + (size_t)r0 * C_ + ct * 64;
        #pragma unroll
        for (int m = 0; m < 4; ++m) {
            int fi = m * 256 + t;
            int r  = fi >> 4;
            int cq = fi & 15;
            float4 vv = *reinterpret_cast<const float4*>(wsrc + (size_t)r * C_ + cq * 4);
            wt[cq * 4 + 0][r] = vv.x;
            wt[cq * 4 + 1][r] = vv.y;
            wt[cq * 4 + 2][r] = vv.z;
            wt[cq * 4 + 3][r] = vv.w;
        }
        __syncthreads();
        #pragma unroll 8
        for (int kk = 0; kk < 64; ++kk) {
            float4 w4 = *reinterpret_cast<const float4*>(&wt[kk][ty * 4]);
            float4 xa = *reinterpret_cast<const float4*>(&xs[kk][tx * 4]);
            float4 xb = *reinterpret_cast<const float4*>(&xs[kk][64 + tx * 4]);
            float wr[4] = {w4.x, w4.y, w4.z, w4.w};
            float xv[8] = {xa.x, xa.y, xa.z, xa.w, xb.x, xb.y, xb.z, xb.w};
            #pragma unroll
            for (int i = 0; i < 4; ++i)
                #pragma unroll
                for (int j = 0; j < 8; ++j)
                    acc[i][j] = fmaf(wr[i], xv[j], acc[i][j]);
        }
        __syncthreads();
    }

    if (rt < 2) {
        float* outp = (rt == 0 ? qo : ko) + (size_t)b * CQ_ * W_;
        #pragma unroll
        for (int i = 0; i < 4; ++i) {
            int r = ty * 4 + i;
            float bb = bias[r];
            float* orow = outp + (size_t)r * W_ + w0;
            float4 o0 = make_float4(acc[i][0] + bb, acc[i][1] + bb, acc[i][2] + bb, acc[i][3] + bb);
            float4 o1 = make_float4(acc[i][4] + bb, acc[i][5] + bb, acc[i][6] + bb, acc[i][7] + bb);
            *reinterpret_cast<float4*>(orow + tx * 4) = o0;
            *reinterpret_cast<float4*>(orow + 64 + tx * 4) = o1;
        }
    } else {
        ushort* outp = vb + (size_t)b * C_ * W_;
        #pragma unroll
        for (int i = 0; i < 4; ++i) {
            int r = r0 + ty * 4 + i;
            float bb = bias[r];
            ushort* orow = outp + (size_t)r * W_ + w0;
            ushort p0[4], p1[4];
            #pragma unroll
            for (int j = 0; j < 4; ++j) { p0[j] = f2bf(acc[i][j] + bb); p1[j] = f2bf(acc[i][4 + j] + bb); }
            unsigned long long v0 = (unsigned long long)p0[0] | ((unsigned long long)p0[1] << 16)
                                  | ((unsigned long long)p0[2] << 32) | ((unsigned long long)p0[3] << 48);
            unsigned long long v1 = (unsigned long long)p1[0] | ((unsigned long long)p1[1] << 16)
                                  | ((unsigned long long)p1[2] << 32) | ((unsigned long long)p1[3] << 48);
            *reinterpret_cast<unsigned long long*>(orow + tx * 4) = v0;
            *reinterpret_cast<unsigned long long*>(orow + 64 + tx * 4) = v1;
        }
    }
}

// ---------------------------------------------------------------------------
// Kernel 2 (round-1, PROVEN): energy E[b,i,j] = sum_q q[b,q,i]*k[b,q,j].
// fp32 VALU, 128x128 tile, K=64 single pass. grid: (16 j, 16 i, B).
// ---------------------------------------------------------------------------
__global__ __launch_bounds__(256) void k_energy(
    const float* __restrict__ q, const float* __restrict__ k, float* __restrict__ E)
{
    const int b  = blockIdx.z;
    const int i0 = blockIdx.y * 128;
    const int j0 = blockIdx.x * 128;

    __shared__ __align__(16) float qs[64][132];
    __shared__ __align__(16) float ks[64][132];

    const int t  = threadIdx.x;
    const int tx = t & 15, ty = t >> 4;

    const float* qsrc = q + (size_t)b * CQ_ * W_ + i0;
    const float* ksrc = k + (size_t)b * CQ_ * W_ + j0;
    #pragma unroll
    for (int m = 0; m < 8; ++m) {
        int fi = m * 256 + t;
        int qq = fi >> 5;
        int iq = fi & 31;
        *reinterpret_cast<float4*>(&qs[qq][iq * 4]) =
            *reinterpret_cast<const float4*>(qsrc + (size_t)qq * W_ + iq * 4);
        *reinterpret_cast<float4*>(&ks[qq][iq * 4]) =
            *reinterpret_cast<const float4*>(ksrc + (size_t)qq * W_ + iq * 4);
    }
    __syncthreads();

    float acc[8][8];
    #pragma unroll
    for (int i = 0; i < 8; ++i)
        #pragma unroll
        for (int j = 0; j < 8; ++j) acc[i][j] = 0.f;

    #pragma unroll 8
    for (int kk = 0; kk < 64; ++kk) {
        float4 qa = *reinterpret_cast<const float4*>(&qs[kk][ty * 4]);
        float4 qb = *reinterpret_cast<const float4*>(&qs[kk][64 + ty * 4]);
        float4 ka = *reinterpret_cast<const float4*>(&ks[kk][tx * 4]);
        float4 kb = *reinterpret_cast<const float4*>(&ks[kk][64 + tx * 4]);
        float qv[8] = {qa.x, qa.y, qa.z, qa.w, qb.x, qb.y, qb.z, qb.w};
        float kv[8] = {ka.x, ka.y, ka.z, ka.w, kb.x, kb.y, kb.z, kb.w};
        #pragma unroll
        for (int i = 0; i < 8; ++i)
            #pragma unroll
            for (int j = 0; j < 8; ++j)
                acc[i][j] = fmaf(qv[i], kv[j], acc[i][j]);
    }

    float* erow0 = E + ((size_t)b * W_ + i0) * W_ + j0;
    #pragma unroll
    for (int ih = 0; ih < 8; ++ih) {
        int ii = ((ih & 4) << 4) + ty * 4 + (ih & 3);
        float* er = erow0 + (size_t)ii * W_;
        float4 o0 = make_float4(acc[ih][0], acc[ih][1], acc[ih][2], acc[ih][3]);
        float4 o1 = make_float4(acc[ih][4], acc[ih][5], acc[ih][6], acc[ih][7]);
        *reinterpret_cast<float4*>(er + tx * 4) = o0;
        *reinterpret_cast<float4*>(er + 64 + tx * 4) = o1;
    }
}

// ---------------------------------------------------------------------------
// Kernel 3 (round-1, PROVEN): per-row softmax stats.
// grid: (W, B); 256 threads per row.
// ---------------------------------------------------------------------------
__global__ __launch_bounds__(256) void k_stats(const float* __restrict__ E,
                                               float* __restrict__ mrow,
                                               float* __restrict__ srow)
{
    const int i = blockIdx.x;
    const int b = blockIdx.y;
    const float* row = E + ((size_t)b * W_ + i) * W_;
    const int t = threadIdx.x;

    float v8[8];
    float lm = -3.0e38f;
    #pragma unroll
    for (int m = 0; m < 8; ++m) {
        v8[m] = row[m * 256 + t];
        lm = fmaxf(lm, v8[m]);
    }
    #pragma unroll
    for (int off = 32; off >= 1; off >>= 1)
        lm = fmaxf(lm, __shfl_xor(lm, off));

    __shared__ float red[8];
    const int wv = t >> 6;
    if ((t & 63) == 0) red[wv] = lm;
    __syncthreads();
    const float bm = fmaxf(fmaxf(red[0], red[1]), fmaxf(red[2], red[3]));

    float ls = 0.f;
    #pragma unroll
    for (int m = 0; m < 8; ++m) ls += __expf(v8[m] - bm);
    #pragma unroll
    for (int off = 32; off >= 1; off >>= 1)
        ls += __shfl_xor(ls, off);
    if ((t & 63) == 0) red[4 + wv] = ls;
    __syncthreads();
    if (t == 0) {
        const float bs = red[4] + red[5] + red[6] + red[7];
        mrow[(size_t)b * W_ + i] = bm;
        srow[(size_t)b * W_ + i] = 1.0f / bs;
    }
}

// ---------------------------------------------------------------------------
// Kernel 4 (UNDER TEST): out = gamma * V @ P^T + x via MFMA.
// P computed on the fly from fp32 E + (m, sinv); V bf16; XOR-swizzled LDS.
// Tile: 128c x 128i, j staged in 64-chunks. grid: (16 i, 4 c, B), 256 thr.
// ---------------------------------------------------------------------------
__global__ __launch_bounds__(256) void k_pv(
    const ushort* __restrict__ vb, const float* __restrict__ E,
    const float* __restrict__ mrow, const float* __restrict__ srow,
    const float* __restrict__ x, const float* __restrict__ gamma,
    float* __restrict__ out)
{
    const int b  = blockIdx.z;
    const int c0 = blockIdx.y * 128;
    const int i0 = blockIdx.x * 128;

    __shared__ __align__(16) ushort Vt[128 * 64];
    __shared__ __align__(16) ushort Pt[128 * 64];

    const int t = threadIdx.x, l = t & 63, wid = t >> 6;
    const int wi = wid & 1, wc = wid >> 1;       // wave tile: 64c x 64i
    const int lr = l & 15, lk = (l >> 4) * 8;

    // Staging coords (fixed per thread): 128 rows x 8 chunks of 8 bf16.
    int srow4[4], scc4[4];
    float mi4[4], si4[4];
    #pragma unroll
    for (int m = 0; m < 4; ++m) {
        int fi = m * 256 + t;
        srow4[m] = fi >> 3;
        scc4[m]  = fi & 7;
        mi4[m] = mrow[(size_t)b * W_ + i0 + srow4[m]];
        si4[m] = srow[(size_t)b * W_ + i0 + srow4[m]];
    }

    // Fragment LDS indices (ushort units), jt-invariant. idx ^= ((row&7)<<3).
    int idxA[4][2], idxB[4][2];
    #pragma unroll
    for (int f = 0; f < 4; ++f)
        #pragma unroll
        for (int kc = 0; kc < 2; ++kc) {
            int rowA = wc * 64 + f * 16 + lr;
            int rowB = wi * 64 + f * 16 + lr;
            idxA[f][kc] = ((rowA * 64) + kc * 32 + lk) ^ ((rowA & 7) << 3);
            idxB[f][kc] = ((rowB * 64) + kc * 32 + lk) ^ ((rowB & 7) << 3);
        }

    f32x4 acc[4][4];
    #pragma unroll
    for (int i = 0; i < 4; ++i)
        #pragma unroll
        for (int j = 0; j < 4; ++j) acc[i][j] = (f32x4){0.f, 0.f, 0.f, 0.f};

    const ushort* vbase = vb + ((size_t)b * C_ + c0) * W_;
    const float*  ebase = E + ((size_t)b * W_ + i0) * W_;

    for (int jt = 0; jt < 32; ++jt) {
        const int j0 = jt * 64;
        // --- stage V tile [128c][64j], swizzled ---
        #pragma unroll
        for (int m = 0; m < 4; ++m) {
            int row = srow4[m], cc = scc4[m];
            short8 v8 = *reinterpret_cast<const short8*>(vbase + (size_t)row * W_ + j0 + cc * 8);
            int idx = ((row * 64) + cc * 8) ^ ((row & 7) << 3);
            *reinterpret_cast<short8*>(&Vt[idx]) = v8;
        }
        // --- stage P tile [128i][64j], swizzled; P = exp(E-m)*sinv in bf16 ---
        #pragma unroll
        for (int m = 0; m < 4; ++m) {
            int row = srow4[m], cc = scc4[m];
            int idx = ((row * 64) + cc * 8) ^ ((row & 7) << 3);
            const float* eb = ebase + (size_t)row * W_ + j0 + cc * 8;
            float4 e0 = *reinterpret_cast<const float4*>(eb);
            float4 e1 = *reinterpret_cast<const float4*>(eb + 4);
            float mi = mi4[m], si = si4[m];
            short8 ps;
            ps[0] = (short)f2bf(__expf(e0.x - mi) * si);
            ps[1] = (short)f2bf(__expf(e0.y - mi) * si);
            ps[2] = (short)f2bf(__expf(e0.z - mi) * si);
            ps[3] = (short)f2bf(__expf(e0.w - mi) * si);
            ps[4] = (short)f2bf(__expf(e1.x - mi) * si);
            ps[5] = (short)f2bf(__expf(e1.y - mi) * si);
            ps[6] = (short)f2bf(__expf(e1.z - mi) * si);
            ps[7] = (short)f2bf(__expf(e1.w - mi) * si);
            *reinterpret_cast<short8*>(&Pt[idx]) = ps;
        }
        __syncthreads();
        // --- MFMA: acc[c-frag][i-frag] += V-frag * P-frag ---
        #pragma unroll
        for (int kc = 0; kc < 2; ++kc) {
            short8 a[4], p[4];
            #pragma unroll
            for (int f = 0; f < 4; ++f) {
                a[f] = *reinterpret_cast<const short8*>(&Vt[idxA[f][kc]]);
                p[f] = *reinterpret_cast<const short8*>(&Pt[idxB[f][kc]]);
            }
            #pragma unroll
            for (int fc = 0; fc < 4; ++fc)
                #pragma unroll
                for (int fi = 0; fi < 4; ++fi)
                    acc[fc][fi] = __builtin_amdgcn_mfma_f32_16x16x32_bf16(a[fc], p[fi], acc[fc][fi], 0, 0, 0);
        }
        __syncthreads();
    }

    // --- epilogue: out = gamma*acc + x ---
    const float g = gamma[0];
    #pragma unroll
    for (int fc = 0; fc < 4; ++fc) {
        int c = c0 + wc * 64 + fc * 16 + (l >> 4) * 4;
        #pragma unroll
        for (int fi = 0; fi < 4; ++fi) {
            int icol = i0 + wi * 64 + fi * 16 + lr;
            #pragma unroll
            for (int r = 0; r < 4; ++r) {
                size_t addr = ((size_t)b * C_ + c + r) * W_ + icol;
                out[addr] = g * acc[fc][fi][r] + x[addr];
            }
        }
    }
}

// ---------------------------------------------------------------------------
extern "C" void kernel_launch(void* const* d_in, const int* in_sizes, int n_in,
                              void* d_out, int out_size, void* d_ws, size_t ws_size,
                              hipStream_t stream)
{
    const float* x     = (const float*)d_in[0];
    const float* Wq    = (const float*)d_in[1];
    const float* bq    = (const float*)d_in[2];
    const float* Wk    = (const float*)d_in[3];
    const float* bk    = (const float*)d_in[4];
    const float* Wv    = (const float*)d_in[5];
    const float* bv    = (const float*)d_in[6];
    const float* gamma = (const float*)d_in[7];
    float* out = (float*)d_out;
    float* ws  = (float*)d_ws;

    float*  q    = ws + OFF_Q;
    float*  k    = ws + OFF_K;
    ushort* vbf  = (ushort*)(ws + OFF_VB);
    float*  E    = ws + OFF_E;
    float*  mrow = ws + OFF_M;
    float*  srow = ws + OFF_S;

    hipLaunchKernelGGL(k_proj,   dim3(W_ / 128, 10, B_), dim3(256), 0, stream,
                       x, Wq, bq, Wk, bk, Wv, bv, q, k, vbf);
    hipLaunchKernelGGL(k_energy, dim3(W_ / 128, W_ / 128, B_), dim3(256), 0, stream,
                       q, k, E);
    hipLaunchKernelGGL(k_stats,  dim3(W_, B_, 1), dim3(256), 0, stream,
                       E, mrow, srow);
    hipLaunchKernelGGL(k_pv,     dim3(W_ / 128, C_ / 128, B_), dim3(256), 0, stream,
                       vbf, E, mrow, srow, x, gamma, out);
}

// Round 6
// 299.262 us; speedup vs baseline: 2.5274x; 1.2361x over previous
//
#include <hip/hip_runtime.h>

// Problem constants: B=8, C=512, Cq=64, W=2048.
#define B_  8
#define C_  512
#define CQ_ 64
#define W_  2048
#define NROW 640   // stacked output rows: 64 q + 64 k + 512 v

typedef __attribute__((ext_vector_type(8))) short  short8;   // 8 bf16 (MFMA A/B frag)
typedef __attribute__((ext_vector_type(4))) float  f32x4;    // MFMA C/D frag
typedef unsigned short ushort;
typedef unsigned long long ull;

// Workspace layout (float slots). Total = 39,878,656 floats = 159.5 MB.
static constexpr size_t OFF_Q  = 0;                                  // q fp32 [B][64][W]
static constexpr size_t OFF_K  = OFF_Q  + (size_t)B_ * CQ_ * W_;     // k fp32 [B][64][W]
static constexpr size_t OFF_VB = OFF_K  + (size_t)B_ * CQ_ * W_;     // V bf16 [B][C][W]
static constexpr size_t OFF_E  = OFF_VB + (size_t)B_ * C_ * W_ / 2;  // E fp32 [B][W][W]
static constexpr size_t OFF_M  = OFF_E  + (size_t)B_ * W_ * W_;      // m [B][W]
static constexpr size_t OFF_S  = OFF_M  + (size_t)B_ * W_;           // sinv [B][W]
// Aliased INSIDE the E region (dead before k_energy writes E):
static constexpr size_t OFF_XTH = OFF_E;                             // xT hi bf16 [B][W][C]
static constexpr size_t OFF_XTL = OFF_XTH + (size_t)B_ * W_ * C_ / 2;
static constexpr size_t OFF_WH  = OFF_XTL + (size_t)B_ * W_ * C_ / 2; // Wall hi bf16 [640][C]
static constexpr size_t OFF_WL  = OFF_WH  + (size_t)NROW * C_ / 2;    // Wall lo

static __device__ __forceinline__ ushort f2bf(float f) {
    unsigned int u = __builtin_bit_cast(unsigned int, f);
    u += 0x7fffu + ((u >> 16) & 1u);          // round-to-nearest-even
    return (ushort)(u >> 16);
}
static __device__ __forceinline__ float bf2f(ushort h) {
    unsigned int u = ((unsigned int)h) << 16;
    return __builtin_bit_cast(float, u);
}
static __device__ __forceinline__ ull pack4(const ushort* p) {
    return (ull)p[0] | ((ull)p[1] << 16) | ((ull)p[2] << 32) | ((ull)p[3] << 48);
}

// ---------------------------------------------------------------------------
// Kernel 0a: pack Wq/Wk/Wv into stacked [640][512] hi/lo split-bf16.
// grid: 320 blocks x 256 thr, 4 elements/thread.
// ---------------------------------------------------------------------------
__global__ __launch_bounds__(256) void k_wsplit(
    const float* __restrict__ Wq, const float* __restrict__ Wk,
    const float* __restrict__ Wv, ushort* __restrict__ wh, ushort* __restrict__ wl)
{
    const int idx = (blockIdx.x * 256 + threadIdx.x) * 4;   // < 640*512
    const int row = idx >> 9, col = idx & 511;
    const float* src;
    if (row < 64)       src = Wq + (size_t)row * C_ + col;
    else if (row < 128) src = Wk + (size_t)(row - 64) * C_ + col;
    else                src = Wv + (size_t)(row - 128) * C_ + col;
    float4 v = *reinterpret_cast<const float4*>(src);
    float vv[4] = {v.x, v.y, v.z, v.w};
    ushort h[4], lo[4];
    #pragma unroll
    for (int j = 0; j < 4; ++j) {
        h[j]  = f2bf(vv[j]);
        lo[j] = f2bf(vv[j] - bf2f(h[j]));
    }
    *reinterpret_cast<ull*>(wh + idx) = pack4(h);
    *reinterpret_cast<ull*>(wl + idx) = pack4(lo);
}

// ---------------------------------------------------------------------------
// Kernel 0b: transpose x [B][C][W] fp32 -> xT hi/lo bf16 [B][W][C].
// grid: (W/64, C/64, B), 256 thr, 64x64 tile via LDS.
// ---------------------------------------------------------------------------
__global__ __launch_bounds__(256) void k_xt(
    const float* __restrict__ x, ushort* __restrict__ xth, ushort* __restrict__ xtl)
{
    const int b = blockIdx.z, c0 = blockIdx.y * 64, w0 = blockIdx.x * 64;
    __shared__ float ts[64][65];
    const int t = threadIdx.x;
    #pragma unroll
    for (int m = 0; m < 4; ++m) {
        int fi = m * 256 + t;
        int c = fi >> 4, c4 = fi & 15;
        float4 v = *reinterpret_cast<const float4*>(x + ((size_t)b * C_ + c0 + c) * W_ + w0 + c4 * 4);
        ts[c][c4 * 4 + 0] = v.x; ts[c][c4 * 4 + 1] = v.y;
        ts[c][c4 * 4 + 2] = v.z; ts[c][c4 * 4 + 3] = v.w;
    }
    __syncthreads();
    #pragma unroll
    for (int m = 0; m < 4; ++m) {
        int w  = m * 16 + (t >> 4);
        int cc = (t & 15) * 4;
        ushort h[4], lo[4];
        #pragma unroll
        for (int j = 0; j < 4; ++j) {
            float v = ts[cc + j][w];
            h[j]  = f2bf(v);
            lo[j] = f2bf(v - bf2f(h[j]));
        }
        size_t base = ((size_t)b * W_ + w0 + w) * C_ + c0 + cc;
        *reinterpret_cast<ull*>(xth + base) = pack4(h);
        *reinterpret_cast<ull*>(xtl + base) = pack4(lo);
    }
}

// ---------------------------------------------------------------------------
// Kernel 1 (UNDER TEST): projection GEMM via MFMA register fragments.
// Out[r][w] = sum_c Wall[r][c] * x[c][w], r in [0,640): q(64)|k(64)|v(512).
// Q/K rows: split-bf16 (hh+lh+hl, ~fp32-accurate). V rows: hh only (bf16-level).
// grid: (W/64=32, B), 512 thr = 8 waves. Wave's m-groups: {wid, wid+8, ..., wid+32}
// -> each wave gets exactly 1 Q/K group (m==0) + 4 V groups: balanced 448 MFMA.
// No LDS, no barriers; B-frags identical across waves (L1 reuse), A rows L2-resident.
// ---------------------------------------------------------------------------
__global__ __launch_bounds__(512) void k_projm(
    const ushort* __restrict__ wh, const ushort* __restrict__ wl,
    const ushort* __restrict__ xth, const ushort* __restrict__ xtl,
    const float* __restrict__ bq, const float* __restrict__ bk,
    const float* __restrict__ bv,
    float* __restrict__ qo, float* __restrict__ ko, ushort* __restrict__ vb)
{
    const int b = blockIdx.y, w0 = blockIdx.x * 64;
    const int t = threadIdx.x, l = t & 63, wid = t >> 6;
    const int lr = l & 15, lkb = (l >> 4) * 8;

    f32x4 acc[5][4];
    #pragma unroll
    for (int m = 0; m < 5; ++m)
        #pragma unroll
        for (int n = 0; n < 4; ++n) acc[m][n] = (f32x4){0.f, 0.f, 0.f, 0.f};

    const size_t xbase = ((size_t)b * W_ + w0 + lr) * C_ + lkb;

    for (int kc = 0; kc < 16; ++kc) {
        short8 bhf[4], blf[4];
        #pragma unroll
        for (int n = 0; n < 4; ++n) {
            bhf[n] = *reinterpret_cast<const short8*>(xth + xbase + (size_t)n * 16 * C_ + kc * 32);
            blf[n] = *reinterpret_cast<const short8*>(xtl + xbase + (size_t)n * 16 * C_ + kc * 32);
        }
        #pragma unroll
        for (int m = 0; m < 5; ++m) {
            const int arow = (wid + m * 8) * 16 + lr;
            const size_t abase = (size_t)arow * C_ + kc * 32 + lkb;
            short8 ah = *reinterpret_cast<const short8*>(wh + abase);
            #pragma unroll
            for (int n = 0; n < 4; ++n)
                acc[m][n] = __builtin_amdgcn_mfma_f32_16x16x32_bf16(ah, bhf[n], acc[m][n], 0, 0, 0);
            if (m == 0) {   // Q/K group: add lo-plane cross terms
                short8 al = *reinterpret_cast<const short8*>(wl + abase);
                #pragma unroll
                for (int n = 0; n < 4; ++n) {
                    acc[m][n] = __builtin_amdgcn_mfma_f32_16x16x32_bf16(al, bhf[n], acc[m][n], 0, 0, 0);
                    acc[m][n] = __builtin_amdgcn_mfma_f32_16x16x32_bf16(ah, blf[n], acc[m][n], 0, 0, 0);
                }
            }
        }
    }

    // Epilogue: D row = (l>>4)*4 + reg (validated m89 layout), col = lr.
    #pragma unroll
    for (int m = 0; m < 5; ++m) {
        const int rbase16 = (wid + m * 8) * 16;
        #pragma unroll
        for (int n = 0; n < 4; ++n) {
            const int wcol = w0 + n * 16 + lr;
            #pragma unroll
            for (int r = 0; r < 4; ++r) {
                const int row = rbase16 + (l >> 4) * 4 + r;
                float val = acc[m][n][r];
                if (rbase16 < 64) {
                    val += bq[row];
                    qo[((size_t)b * CQ_ + row) * W_ + wcol] = val;
                } else if (rbase16 < 128) {
                    const int rl = row - 64;
                    val += bk[rl];
                    ko[((size_t)b * CQ_ + rl) * W_ + wcol] = val;
                } else {
                    const int rl = row - 128;
                    val += bv[rl];
                    vb[((size_t)b * C_ + rl) * W_ + wcol] = f2bf(val);
                }
            }
        }
    }
}

// ---------------------------------------------------------------------------
// Kernel 2 (PROVEN): energy E[b,i,j] = sum_q q[b,q,i]*k[b,q,j]. fp32 VALU.
// ---------------------------------------------------------------------------
__global__ __launch_bounds__(256) void k_energy(
    const float* __restrict__ q, const float* __restrict__ k, float* __restrict__ E)
{
    const int b  = blockIdx.z;
    const int i0 = blockIdx.y * 128;
    const int j0 = blockIdx.x * 128;

    __shared__ __align__(16) float qs[64][132];
    __shared__ __align__(16) float ks[64][132];

    const int t  = threadIdx.x;
    const int tx = t & 15, ty = t >> 4;

    const float* qsrc = q + (size_t)b * CQ_ * W_ + i0;
    const float* ksrc = k + (size_t)b * CQ_ * W_ + j0;
    #pragma unroll
    for (int m = 0; m < 8; ++m) {
        int fi = m * 256 + t;
        int qq = fi >> 5;
        int iq = fi & 31;
        *reinterpret_cast<float4*>(&qs[qq][iq * 4]) =
            *reinterpret_cast<const float4*>(qsrc + (size_t)qq * W_ + iq * 4);
        *reinterpret_cast<float4*>(&ks[qq][iq * 4]) =
            *reinterpret_cast<const float4*>(ksrc + (size_t)qq * W_ + iq * 4);
    }
    __syncthreads();

    float acc[8][8];
    #pragma unroll
    for (int i = 0; i < 8; ++i)
        #pragma unroll
        for (int j = 0; j < 8; ++j) acc[i][j] = 0.f;

    #pragma unroll 8
    for (int kk = 0; kk < 64; ++kk) {
        float4 qa = *reinterpret_cast<const float4*>(&qs[kk][ty * 4]);
        float4 qb = *reinterpret_cast<const float4*>(&qs[kk][64 + ty * 4]);
        float4 ka = *reinterpret_cast<const float4*>(&ks[kk][tx * 4]);
        float4 kb = *reinterpret_cast<const float4*>(&ks[kk][64 + tx * 4]);
        float qv[8] = {qa.x, qa.y, qa.z, qa.w, qb.x, qb.y, qb.z, qb.w};
        float kv[8] = {ka.x, ka.y, ka.z, ka.w, kb.x, kb.y, kb.z, kb.w};
        #pragma unroll
        for (int i = 0; i < 8; ++i)
            #pragma unroll
            for (int j = 0; j < 8; ++j)
                acc[i][j] = fmaf(qv[i], kv[j], acc[i][j]);
    }

    float* erow0 = E + ((size_t)b * W_ + i0) * W_ + j0;
    #pragma unroll
    for (int ih = 0; ih < 8; ++ih) {
        int ii = ((ih & 4) << 4) + ty * 4 + (ih & 3);
        float* er = erow0 + (size_t)ii * W_;
        float4 o0 = make_float4(acc[ih][0], acc[ih][1], acc[ih][2], acc[ih][3]);
        float4 o1 = make_float4(acc[ih][4], acc[ih][5], acc[ih][6], acc[ih][7]);
        *reinterpret_cast<float4*>(er + tx * 4) = o0;
        *reinterpret_cast<float4*>(er + 64 + tx * 4) = o1;
    }
}

// ---------------------------------------------------------------------------
// Kernel 3 (PROVEN): per-row softmax stats.
// ---------------------------------------------------------------------------
__global__ __launch_bounds__(256) void k_stats(const float* __restrict__ E,
                                               float* __restrict__ mrow,
                                               float* __restrict__ srow)
{
    const int i = blockIdx.x;
    const int b = blockIdx.y;
    const float* row = E + ((size_t)b * W_ + i) * W_;
    const int t = threadIdx.x;

    float v8[8];
    float lm = -3.0e38f;
    #pragma unroll
    for (int m = 0; m < 8; ++m) {
        v8[m] = row[m * 256 + t];
        lm = fmaxf(lm, v8[m]);
    }
    #pragma unroll
    for (int off = 32; off >= 1; off >>= 1)
        lm = fmaxf(lm, __shfl_xor(lm, off));

    __shared__ float red[8];
    const int wv = t >> 6;
    if ((t & 63) == 0) red[wv] = lm;
    __syncthreads();
    const float bm = fmaxf(fmaxf(red[0], red[1]), fmaxf(red[2], red[3]));

    float ls = 0.f;
    #pragma unroll
    for (int m = 0; m < 8; ++m) ls += __expf(v8[m] - bm);
    #pragma unroll
    for (int off = 32; off >= 1; off >>= 1)
        ls += __shfl_xor(ls, off);
    if ((t & 63) == 0) red[4 + wv] = ls;
    __syncthreads();
    if (t == 0) {
        const float bs = red[4] + red[5] + red[6] + red[7];
        mrow[(size_t)b * W_ + i] = bm;
        srow[(size_t)b * W_ + i] = 1.0f / bs;
    }
}

// ---------------------------------------------------------------------------
// Kernel 4 (PROVEN): out = gamma * V @ P^T + x via MFMA, swizzled LDS.
// ---------------------------------------------------------------------------
__global__ __launch_bounds__(256) void k_pv(
    const ushort* __restrict__ vb, const float* __restrict__ E,
    const float* __restrict__ mrow, const float* __restrict__ srow,
    const float* __restrict__ x, const float* __restrict__ gamma,
    float* __restrict__ out)
{
    const int b  = blockIdx.z;
    const int c0 = blockIdx.y * 128;
    const int i0 = blockIdx.x * 128;

    __shared__ __align__(16) ushort Vt[128 * 64];
    __shared__ __align__(16) ushort Pt[128 * 64];

    const int t = threadIdx.x, l = t & 63, wid = t >> 6;
    const int wi = wid & 1, wc = wid >> 1;       // wave tile: 64c x 64i
    const int lr = l & 15, lk = (l >> 4) * 8;

    int srow4[4], scc4[4];
    float mi4[4], si4[4];
    #pragma unroll
    for (int m = 0; m < 4; ++m) {
        int fi = m * 256 + t;
        srow4[m] = fi >> 3;
        scc4[m]  = fi & 7;
        mi4[m] = mrow[(size_t)b * W_ + i0 + srow4[m]];
        si4[m] = srow[(size_t)b * W_ + i0 + srow4[m]];
    }

    int idxA[4][2], idxB[4][2];
    #pragma unroll
    for (int f = 0; f < 4; ++f)
        #pragma unroll
        for (int kc = 0; kc < 2; ++kc) {
            int rowA = wc * 64 + f * 16 + lr;
            int rowB = wi * 64 + f * 16 + lr;
            idxA[f][kc] = ((rowA * 64) + kc * 32 + lk) ^ ((rowA & 7) << 3);
            idxB[f][kc] = ((rowB * 64) + kc * 32 + lk) ^ ((rowB & 7) << 3);
        }

    f32x4 acc[4][4];
    #pragma unroll
    for (int i = 0; i < 4; ++i)
        #pragma unroll
        for (int j = 0; j < 4; ++j) acc[i][j] = (f32x4){0.f, 0.f, 0.f, 0.f};

    const ushort* vbase = vb + ((size_t)b * C_ + c0) * W_;
    const float*  ebase = E + ((size_t)b * W_ + i0) * W_;

    for (int jt = 0; jt < 32; ++jt) {
        const int j0 = jt * 64;
        #pragma unroll
        for (int m = 0; m < 4; ++m) {
            int row = srow4[m], cc = scc4[m];
            short8 v8 = *reinterpret_cast<const short8*>(vbase + (size_t)row * W_ + j0 + cc * 8);
            int idx = ((row * 64) + cc * 8) ^ ((row & 7) << 3);
            *reinterpret_cast<short8*>(&Vt[idx]) = v8;
        }
        #pragma unroll
        for (int m = 0; m < 4; ++m) {
            int row = srow4[m], cc = scc4[m];
            int idx = ((row * 64) + cc * 8) ^ ((row & 7) << 3);
            const float* eb = ebase + (size_t)row * W_ + j0 + cc * 8;
            float4 e0 = *reinterpret_cast<const float4*>(eb);
            float4 e1 = *reinterpret_cast<const float4*>(eb + 4);
            float mi = mi4[m], si = si4[m];
            short8 ps;
            ps[0] = (short)f2bf(__expf(e0.x - mi) * si);
            ps[1] = (short)f2bf(__expf(e0.y - mi) * si);
            ps[2] = (short)f2bf(__expf(e0.z - mi) * si);
            ps[3] = (short)f2bf(__expf(e0.w - mi) * si);
            ps[4] = (short)f2bf(__expf(e1.x - mi) * si);
            ps[5] = (short)f2bf(__expf(e1.y - mi) * si);
            ps[6] = (short)f2bf(__expf(e1.z - mi) * si);
            ps[7] = (short)f2bf(__expf(e1.w - mi) * si);
            *reinterpret_cast<short8*>(&Pt[idx]) = ps;
        }
        __syncthreads();
        #pragma unroll
        for (int kc = 0; kc < 2; ++kc) {
            short8 a[4], p[4];
            #pragma unroll
            for (int f = 0; f < 4; ++f) {
                a[f] = *reinterpret_cast<const short8*>(&Vt[idxA[f][kc]]);
                p[f] = *reinterpret_cast<const short8*>(&Pt[idxB[f][kc]]);
            }
            #pragma unroll
            for (int fc = 0; fc < 4; ++fc)
                #pragma unroll
                for (int fi = 0; fi < 4; ++fi)
                    acc[fc][fi] = __builtin_amdgcn_mfma_f32_16x16x32_bf16(a[fc], p[fi], acc[fc][fi], 0, 0, 0);
        }
        __syncthreads();
    }

    const float g = gamma[0];
    #pragma unroll
    for (int fc = 0; fc < 4; ++fc) {
        int c = c0 + wc * 64 + fc * 16 + (l >> 4) * 4;
        #pragma unroll
        for (int fi = 0; fi < 4; ++fi) {
            int icol = i0 + wi * 64 + fi * 16 + lr;
            #pragma unroll
            for (int r = 0; r < 4; ++r) {
                size_t addr = ((size_t)b * C_ + c + r) * W_ + icol;
                out[addr] = g * acc[fc][fi][r] + x[addr];
            }
        }
    }
}

// ---------------------------------------------------------------------------
extern "C" void kernel_launch(void* const* d_in, const int* in_sizes, int n_in,
                              void* d_out, int out_size, void* d_ws, size_t ws_size,
                              hipStream_t stream)
{
    const float* x     = (const float*)d_in[0];
    const float* Wq    = (const float*)d_in[1];
    const float* bq    = (const float*)d_in[2];
    const float* Wk    = (const float*)d_in[3];
    const float* bk    = (const float*)d_in[4];
    const float* Wv    = (const float*)d_in[5];
    const float* bv    = (const float*)d_in[6];
    const float* gamma = (const float*)d_in[7];
    float* out = (float*)d_out;
    float* ws  = (float*)d_ws;

    float*  q    = ws + OFF_Q;
    float*  k    = ws + OFF_K;
    ushort* vbf  = (ushort*)(ws + OFF_VB);
    float*  E    = ws + OFF_E;
    float*  mrow = ws + OFF_M;
    float*  srow = ws + OFF_S;
    ushort* xth  = (ushort*)(ws + OFF_XTH);
    ushort* xtl  = (ushort*)(ws + OFF_XTL);
    ushort* wh   = (ushort*)(ws + OFF_WH);
    ushort* wl   = (ushort*)(ws + OFF_WL);

    hipLaunchKernelGGL(k_wsplit, dim3(NROW * C_ / 1024, 1, 1), dim3(256), 0, stream,
                       Wq, Wk, Wv, wh, wl);
    hipLaunchKernelGGL(k_xt,     dim3(W_ / 64, C_ / 64, B_), dim3(256), 0, stream,
                       x, xth, xtl);
    hipLaunchKernelGGL(k_projm,  dim3(W_ / 64, B_, 1), dim3(512), 0, stream,
                       wh, wl, xth, xtl, bq, bk, bv, q, k, vbf);
    hipLaunchKernelGGL(k_energy, dim3(W_ / 128, W_ / 128, B_), dim3(256), 0, stream,
                       q, k, E);
    hipLaunchKernelGGL(k_stats,  dim3(W_, B_, 1), dim3(256), 0, stream,
                       E, mrow, srow);
    hipLaunchKernelGGL(k_pv,     dim3(W_ / 128, C_ / 128, B_), dim3(256), 0, stream,
                       vbf, E, mrow, srow, x, gamma, out);
}